// Round 3
// baseline (842.949 us; speedup 1.0000x reference)
//
#include <hip/hip_runtime.h>
#include <hip/hip_bf16.h>

// Problem constants (match reference)
constexpr int NN  = 65536;           // nodes
constexpr int EE  = 262144;          // edges before self loops
constexpr int E2  = EE + NN;         // 327680 edges with self loops
constexpr int BB  = 2048;            // graphs
constexpr int HH  = 4;               // heads
constexpr int DD  = 192;             // per-head dim
constexpr int HD  = 768;             // hidden
constexpr int LL  = 2;               // layers
constexpr float EPS = 1e-5f;
constexpr float SLOPE = 0.2f;

typedef __attribute__((ext_vector_type(8))) short short8;   // 8 bf16 (4 VGPRs)
typedef __attribute__((ext_vector_type(4))) float f32x4;    // MFMA C/D
typedef __hip_bfloat16 bf16;

// ---------------------------------------------------------------------------
__global__ void zero_k(float* __restrict__ p, int n) {
    int i = blockIdx.x * 256 + threadIdx.x;
    if (i < n) p[i] = 0.f;
}

// fp32 -> bf16 convert (4 elements/thread)
__global__ void conv_k(const float4* __restrict__ src, bf16* __restrict__ dst, int n4) {
    int i = blockIdx.x * 256 + threadIdx.x;
    if (i >= n4) return;
    float4 v = src[i];
    bf16* o = dst + (size_t)i * 4;
    o[0] = __float2bfloat16(v.x); o[1] = __float2bfloat16(v.y);
    o[2] = __float2bfloat16(v.z); o[3] = __float2bfloat16(v.w);
}

// All 3 weight matrices (W0, W1, out_w): [k][n] fp32 -> [n][k] bf16, one dispatch
__global__ __launch_bounds__(256) void wconv3_k(const float* __restrict__ W,
                                                const float* __restrict__ OW,
                                                bf16* __restrict__ Wt3) {
    __shared__ float tile[32][33];
    const float* src = (blockIdx.z < 2) ? (W + (size_t)blockIdx.z * HD * HD) : OW;
    bf16* dst = Wt3 + (size_t)blockIdx.z * HD * HD;
    int bx = blockIdx.x * 32;   // n base
    int by = blockIdx.y * 32;   // k base
    int tx = threadIdx.x & 31, ty = threadIdx.x >> 5;   // ty 0..7
    #pragma unroll
    for (int r = 0; r < 32; r += 8)
        tile[ty + r][tx] = src[(size_t)(by + ty + r) * HD + bx + tx];
    __syncthreads();
    #pragma unroll
    for (int r = 0; r < 32; r += 8)
        dst[(size_t)(bx + ty + r) * HD + by + tx] = __float2bfloat16(tile[tx][ty + r]);
}

// ---------------------------------------------------------------------------
__device__ __forceinline__ void load16_lds(const void* g, void* l) {
    __builtin_amdgcn_global_load_lds(
        (const __attribute__((address_space(1))) unsigned int*)g,
        (__attribute__((address_space(3))) unsigned int*)l, 16, 0, 0);
}

// ---------------------------------------------------------------------------
// 256x256-tile deep-pipelined bf16 GEMM: C[M,768] = A[M,768] @ Bt[768,768]^T
// 8 waves (2Mx4N), BK=32 phases, ring of 4 LDS buffers (128 KiB), depth-3
// prefetch with counted vmcnt(8) across raw barriers (T3+T4), per-phase shape
// per the m201 template: {ds_reads + STAGE | bar | lgkm-wait | setprio(1) |
// 32 MFMA | setprio(0) | vmcnt(8) | bar} -- reads-before-bar lets one wave's
// LDS reads complete under the other wave's MFMA cluster; dual barrier per
// phase creates the wave role-split that makes setprio pay (m218b).
//
// LDS layout (per 32 KiB buffer): A region [0,16K), B region [16K,32K).
// Each region = 16 fragment-blocks of 1024 B; block mb holds rows
// [mb*16,+16) x k[0,32). Granule g (16 B) = slot*16 + row_lo (slot = k/8).
// MFMA ds_read for lane l (row_lo=l&15, k=(l>>4)*8) is granule l ->
// address = base + lane*16: consecutive granules, conflict-free, no XOR
// swizzle. Staging source address is permuted to match (global_load_lds dest
// must be linear base + lane*16; the global source is per-lane arbitrary).
// PROVEN CORRECT (round 2: passed, absmax 0.0078125 unchanged).
//
// Ring safety: wave's ds_reads of buf b drain (lgkm) before its MFMAs; the
// overwriting STAGE is issued >= one full phase later, after a barrier both
// sides crossed -> no WAR race. vmcnt(8)+barrier per phase => tile t+1
// resident for ALL waves (each wave waited its own oldest loads, then met
// at the barrier).
__global__ __launch_bounds__(512, 2) void gemm256_k(
    const bf16* __restrict__ A, const bf16* __restrict__ Bt, bf16* __restrict__ C)
{
    constexpr int K  = HD;        // 768
    constexpr int NT = K / 32;    // 24 K-tiles

    __shared__ __attribute__((aligned(16))) char smem[4 * 32768];   // 128 KiB

    // bijective XCD swizzle: grid = 768 = 8 XCD * 96 chunks
    int bid  = blockIdx.x;
    int flat = (bid & 7) * 96 + (bid >> 3);
    int by   = flat / 3;                 // 0..255 (3 col-blocks of a row strip stay on one XCD)
    int bx   = flat - by * 3;            // 0..2
    int bm   = by * 256, bn = bx * 256;

    int tid  = threadIdx.x;
    int wid  = tid >> 6, lane = tid & 63;
    int wr   = wid >> 2, wc = wid & 3;        // wave -> 128x64 output sub-tile
    int m16  = lane & 15, quad = lane >> 4;   // MFMA fragment coords

    // staging: chunk0 p=tid covers A rows 0..127, chunk1 p=tid+512 rows 128..255
    // p -> row = (p>>6)*16 + (p&15), slot = (p>>4)&3  (slot-major within block)
    int prow = ((tid >> 6) << 4) | (tid & 15);
    int slot = (tid >> 4) & 3;
    const bf16* gA = A  + (size_t)(bm + prow) * K + slot * 8;
    const bf16* gB = Bt + (size_t)(bn + prow) * K + slot * 8;
    char* ldst = smem + tid * 16;   // + (t&3)*32768 (+8192 chunk1, +16384 B region)

    auto STAGE = [&](int t) {
        char* d = ldst + (size_t)(t & 3) * 32768;
        const bf16* a = gA + t * 32;
        const bf16* b = gB + t * 32;
        load16_lds(a,                  d);
        load16_lds(a + (size_t)128*K,  d + 8192);
        load16_lds(b,                  d + 16384);
        load16_lds(b + (size_t)128*K,  d + 24576);
    };

    f32x4 acc[8][4];
    #pragma unroll
    for (int i = 0; i < 8; i++)
        #pragma unroll
        for (int j = 0; j < 4; j++) acc[i][j] = (f32x4)0.f;

    // one pipeline phase: ds_reads (current tile) + optional prefetch STAGE,
    // then barrier -> MFMA cluster at prio 1. Counted vmcnt + bar2 added by
    // the caller (must be a compile-time literal in the asm).
    auto PHASE = [&](int t, int tstage) {
        const char* ab = smem + (size_t)(t & 3) * 32768;
        const char* bb = ab + 16384;
        short8 a[8], b[4];
        #pragma unroll
        for (int n = 0; n < 4; ++n)
            b[n] = *(const short8*)(bb + (wc * 4 + n) * 1024 + lane * 16);
        #pragma unroll
        for (int m = 0; m < 8; ++m)
            a[m] = *(const short8*)(ab + (wr * 8 + m) * 1024 + lane * 16);
        if (tstage >= 0) STAGE(tstage);
        __builtin_amdgcn_s_barrier();          // bar1: issue-phase done
        // (compiler inserts the lgkmcnt waits before first MFMA use)
        __builtin_amdgcn_s_setprio(1);
        #pragma unroll
        for (int m = 0; m < 8; ++m)
            #pragma unroll
            for (int n = 0; n < 4; ++n)
                acc[m][n] = __builtin_amdgcn_mfma_f32_16x16x32_bf16(a[m], b[n], acc[m][n], 0, 0, 0);
        __builtin_amdgcn_s_setprio(0);
    };

    // prologue: stage tiles 0,1,2; wait own oldest 4 (tile 0), meet at barrier
    STAGE(0); STAGE(1); STAGE(2);
    asm volatile("s_waitcnt vmcnt(8)" ::: "memory");
    __builtin_amdgcn_s_barrier();

    // steady state: 8 loads (tiles t+2, t+3) stay in flight across barriers
    for (int t = 0; t < NT - 3; ++t) {
        PHASE(t, t + 3);
        asm volatile("s_waitcnt vmcnt(8)" ::: "memory");
        __builtin_amdgcn_s_barrier();          // bar2: tile t+1 resident
    }
    PHASE(NT - 3, -1);
    asm volatile("s_waitcnt vmcnt(4)" ::: "memory");
    __builtin_amdgcn_s_barrier();
    PHASE(NT - 2, -1);
    asm volatile("s_waitcnt vmcnt(0)" ::: "memory");
    __builtin_amdgcn_s_barrier();
    PHASE(NT - 1, -1);

    // epilogue: C/D layout col=lane&15, row=(lane>>4)*4+reg
    #pragma unroll
    for (int m = 0; m < 8; ++m) {
        int row0 = bm + wr * 128 + m * 16 + quad * 4;
        #pragma unroll
        for (int n = 0; n < 4; ++n) {
            int col = bn + wc * 64 + n * 16 + m16;
            #pragma unroll
            for (int r = 0; r < 4; ++r)
                C[(size_t)(row0 + r) * HD + col] = __float2bfloat16(acc[m][n][r]);
        }
    }
}

// ---------------------------------------------------------------------------
// bf16 MFMA GEMM (128x128 tile) — kept for the final 2048x768 projection.
template <bool BF16_OUT, bool SWIZ>
__global__ __launch_bounds__(256) void gemm_bf16_k(
    const bf16* __restrict__ A, const bf16* __restrict__ Bt,
    float* __restrict__ Cf, bf16* __restrict__ Cb, const float* __restrict__ bias)
{
    constexpr int K = HD;
    __shared__ __attribute__((aligned(16))) short As[128 * 32];
    __shared__ __attribute__((aligned(16))) short Bs[128 * 32];

    int bx, by;
    if (SWIZ) {
        int gid = blockIdx.x;
        int xcd = gid & 7, lid = gid >> 3;
        int sg = lid / 48, sl = lid - sg * 48;
        by = (xcd << 6) + (sg << 3) + (sl & 7);
        bx = sl >> 3;
    } else {
        bx = blockIdx.x; by = blockIdx.y;
    }

    int tid  = threadIdx.x;
    int wave = tid >> 6, lane = tid & 63;
    int wy = wave >> 1, wx = wave & 1;
    int m16 = lane & 15, quad = lane >> 4;
    int bm = by * 128;
    int bn = bx * 128;

    int p0 = wave * 128 + lane;
    int r0 = p0 >> 2, c0 = p0 & 3;
    int p1 = p0 + 64;
    int r1 = p1 >> 2, c1 = p1 & 3;

    const bf16* gA0 = A  + (size_t)(bm + r0) * K + c0 * 8;
    const bf16* gA1 = A  + (size_t)(bm + r1) * K + c1 * 8;
    const bf16* gB0 = Bt + (size_t)(bn + r0) * K + c0 * 8;
    const bf16* gB1 = Bt + (size_t)(bn + r1) * K + c1 * 8;

    f32x4 acc[4][4];
    #pragma unroll
    for (int i = 0; i < 4; i++)
        #pragma unroll
        for (int j = 0; j < 4; j++) acc[i][j] = (f32x4)0.f;

    const short8* Ac = (const short8*)As;
    const short8* Bc = (const short8*)Bs;

    for (int k0 = 0; k0 < K; k0 += 32) {
        load16_lds(gA0 + k0, &As[p0 * 8]);
        load16_lds(gA1 + k0, &As[p1 * 8]);
        load16_lds(gB0 + k0, &Bs[p0 * 8]);
        load16_lds(gB1 + k0, &Bs[p1 * 8]);
        __syncthreads();

        short8 a[4], b[4];
        #pragma unroll
        for (int i = 0; i < 4; i++)
            a[i] = Ac[(wy * 64 + i * 16 + m16) * 4 + quad];
        #pragma unroll
        for (int j = 0; j < 4; j++)
            b[j] = Bc[(wx * 64 + j * 16 + m16) * 4 + quad];
        #pragma unroll
        for (int i = 0; i < 4; i++)
            #pragma unroll
            for (int j = 0; j < 4; j++)
                acc[i][j] = __builtin_amdgcn_mfma_f32_16x16x32_bf16(a[i], b[j], acc[i][j], 0, 0, 0);
        __syncthreads();
    }

    #pragma unroll
    for (int j = 0; j < 4; j++) {
        int col = bn + wx * 64 + j * 16 + m16;
        float badd = (!BF16_OUT && bias) ? bias[col] : 0.f;
        #pragma unroll
        for (int i = 0; i < 4; i++) {
            int row0 = bm + wy * 64 + i * 16 + quad * 4;
            #pragma unroll
            for (int r = 0; r < 4; r++) {
                if (BF16_OUT)
                    Cb[(size_t)(row0 + r) * HD + col] = __float2bfloat16(acc[i][j][r]);
                else
                    Cf[(size_t)(row0 + r) * HD + col] = acc[i][j][r] + badd;
            }
        }
    }
}

// ---------------------------------------------------------------------------
// per-node attention logits: asrc[n][h] = dot(xw[n,h,:], att_src[h,:]).
// Wave per node (4 nodes/block): lane owns 12 contiguous channels (head=lane>>4,
// 16 lanes/head), 16-lane shuffle reduce. All 64 lanes active.
__device__ __forceinline__ float bflo(unsigned u) { return __uint_as_float(u << 16); }
__device__ __forceinline__ float bfhi(unsigned u) { return __uint_as_float(u & 0xffff0000u); }

__global__ __launch_bounds__(256) void alpha_k(
    const bf16* __restrict__ xw,
    const float* __restrict__ asl, const float* __restrict__ adl,
    float* __restrict__ asrc, float* __restrict__ adst)
{
    int wave = threadIdx.x >> 6, lane = threadIdx.x & 63;
    int n = blockIdx.x * 4 + wave;
    int c = lane * 12;                 // == head*192 + (lane&15)*12

    const bf16* row = xw + (size_t)n * HD + c;
    uint2 u0 = *(const uint2*)(row);
    uint2 u1 = *(const uint2*)(row + 4);
    uint2 u2 = *(const uint2*)(row + 8);
    float v[12] = {bflo(u0.x), bfhi(u0.x), bflo(u0.y), bfhi(u0.y),
                   bflo(u1.x), bfhi(u1.x), bflo(u1.y), bfhi(u1.y),
                   bflo(u2.x), bfhi(u2.x), bflo(u2.y), bfhi(u2.y)};

    float4 a0 = *(const float4*)(asl + c);
    float4 a1 = *(const float4*)(asl + c + 4);
    float4 a2 = *(const float4*)(asl + c + 8);
    float4 d0 = *(const float4*)(adl + c);
    float4 d1 = *(const float4*)(adl + c + 4);
    float4 d2 = *(const float4*)(adl + c + 8);
    float aa[12] = {a0.x,a0.y,a0.z,a0.w,a1.x,a1.y,a1.z,a1.w,a2.x,a2.y,a2.z,a2.w};
    float dd[12] = {d0.x,d0.y,d0.z,d0.w,d1.x,d1.y,d1.z,d1.w,d2.x,d2.y,d2.z,d2.w};

    float s1 = 0.f, s2 = 0.f;
    #pragma unroll
    for (int k = 0; k < 12; k++) { s1 += v[k] * aa[k]; s2 += v[k] * dd[k]; }

    #pragma unroll
    for (int off = 1; off < 16; off <<= 1) {
        s1 += __shfl_xor(s1, off, 64);
        s2 += __shfl_xor(s2, off, 64);
    }
    if ((lane & 15) == 0) {
        int head = lane >> 4;
        asrc[(size_t)n * HH + head] = s1;
        adst[(size_t)n * HH + head] = s2;
    }
}

// ---------------------------------------------------------------------------
// CSR build over dst
__global__ void hist_k(const int* __restrict__ ei, int* __restrict__ deg) {
    int e = blockIdx.x * 256 + threadIdx.x;   // grid == E2 exactly
    int dst = (e < EE) ? ei[EE + e] : (e - EE);
    atomicAdd(&deg[dst], 1);
}

__global__ void scan1_k(const int* __restrict__ deg, int* __restrict__ incl,
                        int* __restrict__ blocksum) {
    __shared__ int s[256];
    int t = threadIdx.x, n = blockIdx.x * 256 + t;
    int v = deg[n];
    s[t] = v;
    for (int off = 1; off < 256; off <<= 1) {
        __syncthreads();
        int tmp = (t >= off) ? s[t - off] : 0;
        __syncthreads();
        s[t] += tmp;
    }
    incl[n] = s[t];
    if (t == 255) blocksum[blockIdx.x] = s[255];
}

__global__ void scan2_k(const int* __restrict__ blocksum, int* __restrict__ blockoff) {
    __shared__ int s[256];
    int t = threadIdx.x;
    int v = blocksum[t];
    s[t] = v;
    for (int off = 1; off < 256; off <<= 1) {
        __syncthreads();
        int tmp = (t >= off) ? s[t - off] : 0;
        __syncthreads();
        s[t] += tmp;
    }
    blockoff[t] = s[t] - v;   // exclusive
}

__global__ void scan3_k(const int* __restrict__ deg, const int* __restrict__ blockoff,
                        int* __restrict__ incl_cursor, int* __restrict__ rowstart) {
    int t = threadIdx.x, n = blockIdx.x * 256 + t;
    int rs = blockoff[blockIdx.x] + incl_cursor[n] - deg[n];
    rowstart[n] = rs;
    incl_cursor[n] = rs;       // becomes the fill cursor
    if (n == 0) rowstart[NN] = E2;
}

__global__ void fill_k(const int* __restrict__ ei, int* __restrict__ cursor,
                       int* __restrict__ csr_src) {
    int e = blockIdx.x * 256 + threadIdx.x;
    int src = (e < EE) ? ei[e] : (e - EE);
    int dst = (e < EE) ? ei[EE + e] : (e - EE);
    int pos = atomicAdd(&cursor[dst], 1);
    csr_src[pos] = src;
}

// ---------------------------------------------------------------------------
// Fused GAT aggregation: edge softmax + weighted gather + bias + LayerNorm +
// ReLU + residual. One wave per node, zero barriers. Inner edge loop unrolled
// by 2 to break the readfirstlane-chained gather latency (2 rows in flight).
__global__ __launch_bounds__(256) void agg_k(
    const bf16* __restrict__ xw, const float4* __restrict__ asrc,
    const float4* __restrict__ adst, const int* __restrict__ rowstart,
    const int* __restrict__ csr_src,
    const float* __restrict__ bias_l, const float* __restrict__ gamma_l,
    const float* __restrict__ beta_l, const bf16* __restrict__ h_in,
    bf16* __restrict__ h_out)
{
    __shared__ float s_w[4][64][4];   // per-wave edge weights (4 heads)
    __shared__ int   s_src[4][64];    // per-wave edge sources

    int wave = threadIdx.x >> 6, lane = threadIdx.x & 63;
    int i = blockIdx.x * 4 + wave;    // node
    int c = lane * 12;                // channel base
    int myhead = lane >> 4;           // 16 lanes per head

    int r0 = rowstart[i], r1 = rowstart[i + 1];
    float4 ad = adst[i];

    float acc[12];
    #pragma unroll
    for (int k = 0; k < 12; k++) acc[k] = 0.f;
    float4 den = make_float4(0.f, 0.f, 0.f, 0.f);

    for (int base = r0; base < r1; base += 64) {
        int cnt = min(64, r1 - base);
        float4 w4 = make_float4(0.f, 0.f, 0.f, 0.f);
        if (lane < cnt) {
            int s = csr_src[base + lane];
            s_src[wave][lane] = s;
            float4 a = asrc[s];                       // L2-resident gather
            float t0 = a.x + ad.x; t0 = (t0 > 0.f) ? t0 : SLOPE * t0;
            float t1 = a.y + ad.y; t1 = (t1 > 0.f) ? t1 : SLOPE * t1;
            float t2 = a.z + ad.z; t2 = (t2 > 0.f) ? t2 : SLOPE * t2;
            float t3 = a.w + ad.w; t3 = (t3 > 0.f) ? t3 : SLOPE * t3;
            w4 = make_float4(__expf(t0), __expf(t1), __expf(t2), __expf(t3));
            *(float4*)&s_w[wave][lane][0] = w4;
        }
        den.x += w4.x; den.y += w4.y; den.z += w4.z; den.w += w4.w;

        int e = 0;
        for (; e + 2 <= cnt; e += 2) {
            int src0 = __builtin_amdgcn_readfirstlane(s_src[wave][e]);
            int src1 = __builtin_amdgcn_readfirstlane(s_src[wave][e + 1]);
            float w0 = s_w[wave][e][myhead];
            float w1 = s_w[wave][e + 1][myhead];
            const bf16* row0 = xw + (size_t)src0 * HD + c;
            const bf16* row1 = xw + (size_t)src1 * HD + c;
            uint2 u00 = *(const uint2*)(row0);
            uint2 u01 = *(const uint2*)(row0 + 4);
            uint2 u02 = *(const uint2*)(row0 + 8);
            uint2 u10 = *(const uint2*)(row1);
            uint2 u11 = *(const uint2*)(row1 + 4);
            uint2 u12 = *(const uint2*)(row1 + 8);
            acc[0] += w0 * bflo(u00.x); acc[1]  += w0 * bfhi(u00.x);
            acc[2] += w0 * bflo(u00.y); acc[3]  += w0 * bfhi(u00.y);
            acc[4] += w0 * bflo(u01.x); acc[5]  += w0 * bfhi(u01.x);
            acc[6] += w0 * bflo(u01.y); acc[7]  += w0 * bfhi(u01.y);
            acc[8] += w0 * bflo(u02.x); acc[9]  += w0 * bfhi(u02.x);
            acc[10] += w0 * bflo(u02.y); acc[11] += w0 * bfhi(u02.y);
            acc[0] += w1 * bflo(u10.x); acc[1]  += w1 * bfhi(u10.x);
            acc[2] += w1 * bflo(u10.y); acc[3]  += w1 * bfhi(u10.y);
            acc[4] += w1 * bflo(u11.x); acc[5]  += w1 * bfhi(u11.x);
            acc[6] += w1 * bflo(u11.y); acc[7]  += w1 * bfhi(u11.y);
            acc[8] += w1 * bflo(u12.x); acc[9]  += w1 * bfhi(u12.x);
            acc[10] += w1 * bflo(u12.y); acc[11] += w1 * bfhi(u12.y);
        }
        if (e < cnt) {
            int src = __builtin_amdgcn_readfirstlane(s_src[wave][e]);
            float wv = s_w[wave][e][myhead];
            const bf16* row = xw + (size_t)src * HD + c;
            uint2 u0 = *(const uint2*)(row);
            uint2 u1 = *(const uint2*)(row + 4);
            uint2 u2 = *(const uint2*)(row + 8);
            acc[0] += wv * bflo(u0.x); acc[1]  += wv * bfhi(u0.x);
            acc[2] += wv * bflo(u0.y); acc[3]  += wv * bfhi(u0.y);
            acc[4] += wv * bflo(u1.x); acc[5]  += wv * bfhi(u1.x);
            acc[6] += wv * bflo(u1.y); acc[7]  += wv * bfhi(u1.y);
            acc[8] += wv * bflo(u2.x); acc[9]  += wv * bfhi(u2.x);
            acc[10] += wv * bflo(u2.y); acc[11] += wv * bfhi(u2.y);
        }
    }

    #pragma unroll
    for (int off = 32; off > 0; off >>= 1) {
        den.x += __shfl_xor(den.x, off, 64);
        den.y += __shfl_xor(den.y, off, 64);
        den.z += __shfl_xor(den.z, off, 64);
        den.w += __shfl_xor(den.w, off, 64);
    }
    float deni = (myhead == 0) ? den.x : (myhead == 1) ? den.y
               : (myhead == 2) ? den.z : den.w;
    float inv = 1.f / deni;

    float4 b0 = *(const float4*)(bias_l + c);
    float4 b1 = *(const float4*)(bias_l + c + 4);
    float4 b2 = *(const float4*)(bias_l + c + 8);
    float v[12];
    v[0] = acc[0] * inv + b0.x; v[1]  = acc[1] * inv + b0.y;
    v[2] = acc[2] * inv + b0.z; v[3]  = acc[3] * inv + b0.w;
    v[4] = acc[4] * inv + b1.x; v[5]  = acc[5] * inv + b1.y;
    v[6] = acc[6] * inv + b1.z; v[7]  = acc[7] * inv + b1.w;
    v[8] = acc[8] * inv + b2.x; v[9]  = acc[9] * inv + b2.y;
    v[10] = acc[10] * inv + b2.z; v[11] = acc[11] * inv + b2.w;

    float s = 0.f;
    #pragma unroll
    for (int k = 0; k < 12; k++) s += v[k];
    #pragma unroll
    for (int off = 32; off > 0; off >>= 1) s += __shfl_xor(s, off, 64);
    float mean = s * (1.f / (float)HD);

    float q = 0.f;
    #pragma unroll
    for (int k = 0; k < 12; k++) { float d = v[k] - mean; q += d * d; }
    #pragma unroll
    for (int off = 32; off > 0; off >>= 1) q += __shfl_xor(q, off, 64);
    float rs = rsqrtf(q * (1.f / (float)HD) + EPS);

    float4 g0 = *(const float4*)(gamma_l + c);
    float4 g1 = *(const float4*)(gamma_l + c + 4);
    float4 g2 = *(const float4*)(gamma_l + c + 8);
    float4 e0 = *(const float4*)(beta_l + c);
    float4 e1 = *(const float4*)(beta_l + c + 4);
    float4 e2 = *(const float4*)(beta_l + c + 8);
    float gg[12] = {g0.x,g0.y,g0.z,g0.w,g1.x,g1.y,g1.z,g1.w,g2.x,g2.y,g2.z,g2.w};
    float bb[12] = {e0.x,e0.y,e0.z,e0.w,e1.x,e1.y,e1.z,e1.w,e2.x,e2.y,e2.z,e2.w};

    const bf16* hrow = h_in + (size_t)i * HD + c;
    uint2 hu0 = *(const uint2*)(hrow);
    uint2 hu1 = *(const uint2*)(hrow + 4);
    uint2 hu2 = *(const uint2*)(hrow + 8);
    float hres[12] = {bflo(hu0.x), bfhi(hu0.x), bflo(hu0.y), bfhi(hu0.y),
                      bflo(hu1.x), bfhi(hu1.x), bflo(hu1.y), bfhi(hu1.y),
                      bflo(hu2.x), bfhi(hu2.x), bflo(hu2.y), bfhi(hu2.y)};

    bf16 pk[12];
    #pragma unroll
    for (int k = 0; k < 12; k++) {
        float o = fmaxf((v[k] - mean) * rs * gg[k] + bb[k], 0.f) + hres[k];
        pk[k] = __float2bfloat16(o);
    }
    bf16* orow = h_out + (size_t)i * HD + c;
    *(uint2*)(orow)     = *(const uint2*)&pk[0];
    *(uint2*)(orow + 4) = *(const uint2*)&pk[4];
    *(uint2*)(orow + 8) = *(const uint2*)&pk[8];
}

// ---------------------------------------------------------------------------
// global mean pool per graph -> bf16 hg; 192 threads, 4 ch/thread (uint2)
__global__ __launch_bounds__(192) void pool_k(
    const bf16* __restrict__ h, const int* __restrict__ bv,
    bf16* __restrict__ hg)
{
    int g = blockIdx.x, t = threadIdx.x;
    int lo = 0, hi = NN;
    while (lo < hi) { int mid = (lo + hi) >> 1; if (bv[mid] < g) lo = mid + 1; else hi = mid; }
    int start = lo;
    hi = NN;
    while (lo < hi) { int mid = (lo + hi) >> 1; if (bv[mid] < g + 1) lo = mid + 1; else hi = mid; }
    int end = lo;
    int c = t * 4;
    float a0 = 0.f, a1 = 0.f, a2 = 0.f, a3 = 0.f;
    for (int n = start; n < end; n++) {
        uint2 u = *(const uint2*)(h + (size_t)n * HD + c);
        a0 += bflo(u.x); a1 += bfhi(u.x); a2 += bflo(u.y); a3 += bfhi(u.y);
    }
    float sc = 1.f / fmaxf((float)(end - start), 1.f);
    bf16 pk[4];
    pk[0] = __float2bfloat16(a0 * sc); pk[1] = __float2bfloat16(a1 * sc);
    pk[2] = __float2bfloat16(a2 * sc); pk[3] = __float2bfloat16(a3 * sc);
    *(uint2*)(hg + (size_t)g * HD + c) = *(const uint2*)pk;
}

// ---------------------------------------------------------------------------
extern "C" void kernel_launch(void* const* d_in, const int* in_sizes, int n_in,
                              void* d_out, int out_size, void* d_ws, size_t ws_size,
                              hipStream_t stream)
{
    (void)in_sizes; (void)n_in; (void)out_size; (void)ws_size;
    const float* x       = (const float*)d_in[0];
    const int*   ei      = (const int*)d_in[1];
    const int*   bv      = (const int*)d_in[2];
    const float* W       = (const float*)d_in[3];
    const float* att_src = (const float*)d_in[4];
    const float* att_dst = (const float*)d_in[5];
    const float* bias    = (const float*)d_in[6];
    const float* gamma   = (const float*)d_in[7];
    const float* beta    = (const float*)d_in[8];
    const float* out_w   = (const float*)d_in[9];
    const float* out_b   = (const float*)d_in[10];
    float* out = (float*)d_out;

    char* p = (char*)d_ws;
    size_t off = 0;
    auto take = [&](size_t bytes) -> char* {
        char* r = p + off;
        off = (off + bytes + 255) & ~(size_t)255;
        return r;
    };
    bf16* xw        = (bf16*)take((size_t)NN * HD * 2);   // bf16 projected feats
    bf16* hbf0      = (bf16*)take((size_t)NN * HD * 2);   // h ping
    bf16* hbf1      = (bf16*)take((size_t)NN * HD * 2);   // h pong
    bf16* Wt3       = (bf16*)take((size_t)3 * HD * HD * 2); // W0,W1,out_w bf16^T
    float* asrc     = (float*)take((size_t)NN * HH * 4);
    float* adst     = (float*)take((size_t)NN * HH * 4);
    int*   deg      = (int*)take((size_t)NN * 4);
    int*   rowstart = (int*)take((size_t)(NN + 1) * 4);
    int*   cursor   = (int*)take((size_t)NN * 4);
    int*   blocksum = (int*)take(256 * 4);
    int*   blockoff = (int*)take(256 * 4);
    int*   csr_src  = (int*)take((size_t)E2 * 4);
    bf16*  hg       = (bf16*)take((size_t)BB * HD * 2);

    const int EB = E2 / 256;   // 1280, exact

    // ---- CSR build (topology only, once) ----
    zero_k<<<NN / 256, 256, 0, stream>>>((float*)deg, NN);
    hist_k<<<EB, 256, 0, stream>>>(ei, deg);
    scan1_k<<<NN / 256, 256, 0, stream>>>(deg, cursor, blocksum);
    scan2_k<<<1, 256, 0, stream>>>(blocksum, blockoff);
    scan3_k<<<NN / 256, 256, 0, stream>>>(deg, blockoff, cursor, rowstart);
    fill_k<<<EB, 256, 0, stream>>>(ei, cursor, csr_src);

    // ---- bf16 conversions ----
    conv_k<<<(NN * HD / 4 + 255) / 256, 256, 0, stream>>>((const float4*)x, hbf0, NN * HD / 4);
    wconv3_k<<<dim3(HD / 32, HD / 32, 3), 256, 0, stream>>>(W, out_w, Wt3);

    // ---- layers (ping-pong h buffers) ----
    bf16* hin = hbf0;
    bf16* hout = hbf1;
    for (int l = 0; l < LL; l++) {
        gemm256_k<<<768, 512, 0, stream>>>(hin, Wt3 + (size_t)l * HD * HD, xw);
        alpha_k<<<NN / 4, 256, 0, stream>>>(xw, att_src + (size_t)l * HH * DD,
                                            att_dst + (size_t)l * HH * DD, asrc, adst);
        agg_k<<<NN / 4, 256, 0, stream>>>(xw, (const float4*)asrc, (const float4*)adst,
                                          rowstart, csr_src,
                                          bias + (size_t)l * HD, gamma + (size_t)l * HD,
                                          beta + (size_t)l * HD, hin, hout);
        bf16* tmp = hin; hin = hout; hout = tmp;
    }

    // ---- pooling + output projection (bf16 MFMA, fp32 out) ----
    pool_k<<<BB, 192, 0, stream>>>(hin, bv, hg);
    gemm_bf16_k<false, false><<<dim3(HD / 128, BB / 128), 256, 0, stream>>>(
        hg, Wt3 + (size_t)2 * HD * HD, out, nullptr, out_b);
}

// Round 4
// 829.643 us; speedup vs baseline: 1.0160x; 1.0160x over previous
//
#include <hip/hip_runtime.h>
#include <hip/hip_bf16.h>

// Problem constants (match reference)
constexpr int NN  = 65536;           // nodes
constexpr int EE  = 262144;          // edges before self loops
constexpr int E2  = EE + NN;         // 327680 edges with self loops
constexpr int BB  = 2048;            // graphs
constexpr int HH  = 4;               // heads
constexpr int DD  = 192;             // per-head dim
constexpr int HD  = 768;             // hidden
constexpr int LL  = 2;               // layers
constexpr float EPS = 1e-5f;
constexpr float SLOPE = 0.2f;

typedef __attribute__((ext_vector_type(8))) short short8;   // 8 bf16 (4 VGPRs)
typedef __attribute__((ext_vector_type(4))) float f32x4;    // MFMA C/D
typedef __hip_bfloat16 bf16;

// ---------------------------------------------------------------------------
__global__ void zero_k(float* __restrict__ p, int n) {
    int i = blockIdx.x * 256 + threadIdx.x;
    if (i < n) p[i] = 0.f;
}

// fp32 -> bf16 convert (4 elements/thread)
__global__ void conv_k(const float4* __restrict__ src, bf16* __restrict__ dst, int n4) {
    int i = blockIdx.x * 256 + threadIdx.x;
    if (i >= n4) return;
    float4 v = src[i];
    bf16* o = dst + (size_t)i * 4;
    o[0] = __float2bfloat16(v.x); o[1] = __float2bfloat16(v.y);
    o[2] = __float2bfloat16(v.z); o[3] = __float2bfloat16(v.w);
}

// All 3 weight matrices (W0, W1, out_w): [k][n] fp32 -> [n][k] bf16, one dispatch
__global__ __launch_bounds__(256) void wconv3_k(const float* __restrict__ W,
                                                const float* __restrict__ OW,
                                                bf16* __restrict__ Wt3) {
    __shared__ float tile[32][33];
    const float* src = (blockIdx.z < 2) ? (W + (size_t)blockIdx.z * HD * HD) : OW;
    bf16* dst = Wt3 + (size_t)blockIdx.z * HD * HD;
    int bx = blockIdx.x * 32;   // n base
    int by = blockIdx.y * 32;   // k base
    int tx = threadIdx.x & 31, ty = threadIdx.x >> 5;   // ty 0..7
    #pragma unroll
    for (int r = 0; r < 32; r += 8)
        tile[ty + r][tx] = src[(size_t)(by + ty + r) * HD + bx + tx];
    __syncthreads();
    #pragma unroll
    for (int r = 0; r < 32; r += 8)
        dst[(size_t)(bx + ty + r) * HD + by + tx] = __float2bfloat16(tile[tx][ty + r]);
}

// ---------------------------------------------------------------------------
__device__ __forceinline__ void load16_lds(const void* g, void* l) {
    __builtin_amdgcn_global_load_lds(
        (const __attribute__((address_space(1))) unsigned int*)g,
        (__attribute__((address_space(3))) unsigned int*)l, 16, 0, 0);
}

// ---------------------------------------------------------------------------
// 256x256-tile bf16 GEMM, m201-style fine-phase schedule.
// C[M,768] = A[M,768] @ Bt[768,768]^T.  8 waves (2Mx4N), ring of 4 LDS K-32
// buffers (128 KiB).  Iter = 2 K-tiles (K=64), 4 phases of 16 MFMA:
//   P1: read a0-7,b0-1 (tile t)  + stage 2 chunks(t+2) | bar | lgkm0 | 16 MFMA | bar
//   P2: read b2-3                + stage 2 chunks(t+2) | bar | lgkm0 | 16 MFMA | vmcnt(4) bar
//   P3: read a0-7,b0-1 (tile t+1)+ stage 2 chunks(t+3) | bar | lgkm0 | 16 MFMA | bar
//   P4: read b2-3                + stage 2 chunks(t+3) | bar | lgkm0 | 16 MFMA | vmcnt(4) bar
// vmcnt counted ONCE per K-tile, never 0 in steady state (T3+T4); setprio
// around each MFMA cluster (T5); XCD-aware bijective swizzle (T1).
//
// LDS layout per 32 KiB buffer (PROVEN, round 2/3: passed, 0 bank conflicts):
// A region [0,16K), B region [16K,32K); 16 fragment-blocks of 1024 B each;
// granule = slot*16 + row_lo so the MFMA ds_read for lane l is base+lane*16
// (consecutive granules, conflict-free).  Staging source address is permuted
// to match; global_load_lds dest is linear base + lane*16.
//
// Wait/WAR proof: P2-end vmcnt(4) leaves only this iter's 4 newest loads in
// flight => tile t+1 (staged last iter) resident before P3 reads it.  P4-end
// vmcnt(4) => tile t+2 resident for next iter's P1.  A staged buffer (t+2 ->
// buf (t&3)^2) was last READ as tile t-2 in the previous iter, >=2 barriers
// before the stage issues => no WAR race.  Tail iter (ts=-1) drains vmcnt(0).
__global__ __launch_bounds__(512, 2) void gemm256_k(
    const bf16* __restrict__ A, const bf16* __restrict__ Bt, bf16* __restrict__ C)
{
    constexpr int K  = HD;        // 768
    constexpr int NT = K / 32;    // 24 K-tiles, 12 iters

    __shared__ __attribute__((aligned(16))) char smem[4 * 32768];   // 128 KiB

    // bijective XCD swizzle: grid = 768 = 8 XCD * 96 chunks
    int bid  = blockIdx.x;
    int flat = (bid & 7) * 96 + (bid >> 3);
    int by   = flat / 3;                 // 0..255
    int bx   = flat - by * 3;            // 0..2
    int bm   = by * 256, bn = bx * 256;

    int tid  = threadIdx.x;
    int wid  = tid >> 6, lane = tid & 63;
    int wr   = wid >> 2, wc = wid & 3;        // wave -> 128x64 output sub-tile
    int m16  = lane & 15, quad = lane >> 4;   // MFMA fragment coords

    // staging source permutation: p=tid -> row=(p>>6)*16+(p&15), slot=(p>>4)&3
    int prow = ((tid >> 6) << 4) | (tid & 15);
    int slot = (tid >> 4) & 3;
    const bf16* gA = A  + (size_t)(bm + prow) * K + slot * 8;
    const bf16* gB = Bt + (size_t)(bn + prow) * K + slot * 8;
    char* ldst = smem + tid * 16;

    // chunk k of tile t: k=0 A rows 0-127, k=1 A rows 128-255, k=2 B lo, k=3 B hi
    auto STAGE1 = [&](int t, int k) {
        char* d = ldst + (size_t)(t & 3) * 32768 + k * 8192;
        const bf16* s = ((k < 2) ? gA : gB) + (size_t)t * 32
                      + ((k & 1) ? (size_t)128 * K : 0);
        load16_lds(s, d);
    };

    f32x4 acc[8][4];
    #pragma unroll
    for (int i = 0; i < 8; i++)
        #pragma unroll
        for (int j = 0; j < 4; j++) acc[i][j] = (f32x4)0.f;

    // one K-32 tile = 2 phases (16 MFMA each); ts = tile to stage (-1 none)
    auto TILE2PH = [&](const char* ab, int ts) {
        const char* bb = ab + 16384;
        short8 a[8], b[4];
        // ---- phase A: C-half (m0-7 x n0-1) ----
        #pragma unroll
        for (int m = 0; m < 8; ++m)
            a[m] = *(const short8*)(ab + (wr * 8 + m) * 1024 + lane * 16);
        b[0] = *(const short8*)(bb + (wc * 4 + 0) * 1024 + lane * 16);
        b[1] = *(const short8*)(bb + (wc * 4 + 1) * 1024 + lane * 16);
        if (ts >= 0) { STAGE1(ts, 0); STAGE1(ts, 1); }
        __builtin_amdgcn_s_barrier();
        asm volatile("s_waitcnt lgkmcnt(0)" ::: "memory");
        __builtin_amdgcn_s_setprio(1);
        #pragma unroll
        for (int m = 0; m < 8; ++m) {
            acc[m][0] = __builtin_amdgcn_mfma_f32_16x16x32_bf16(a[m], b[0], acc[m][0], 0, 0, 0);
            acc[m][1] = __builtin_amdgcn_mfma_f32_16x16x32_bf16(a[m], b[1], acc[m][1], 0, 0, 0);
        }
        __builtin_amdgcn_s_setprio(0);
        __builtin_amdgcn_s_barrier();
        // ---- phase B: C-half (m0-7 x n2-3) ----
        b[2] = *(const short8*)(bb + (wc * 4 + 2) * 1024 + lane * 16);
        b[3] = *(const short8*)(bb + (wc * 4 + 3) * 1024 + lane * 16);
        if (ts >= 0) { STAGE1(ts, 2); STAGE1(ts, 3); }
        __builtin_amdgcn_s_barrier();
        asm volatile("s_waitcnt lgkmcnt(0)" ::: "memory");
        __builtin_amdgcn_s_setprio(1);
        #pragma unroll
        for (int m = 0; m < 8; ++m) {
            acc[m][2] = __builtin_amdgcn_mfma_f32_16x16x32_bf16(a[m], b[2], acc[m][2], 0, 0, 0);
            acc[m][3] = __builtin_amdgcn_mfma_f32_16x16x32_bf16(a[m], b[3], acc[m][3], 0, 0, 0);
        }
        __builtin_amdgcn_s_setprio(0);
        // counted vmcnt: once per K-tile, before the closing barrier
        if (ts >= 0) asm volatile("s_waitcnt vmcnt(4)" ::: "memory");
        else         asm volatile("s_waitcnt vmcnt(0)" ::: "memory");
        __builtin_amdgcn_s_barrier();
    };

    // prologue: stage tiles 0,1 fully; drain; sync
    #pragma unroll
    for (int k = 0; k < 4; ++k) STAGE1(0, k);
    #pragma unroll
    for (int k = 0; k < 4; ++k) STAGE1(1, k);
    asm volatile("s_waitcnt vmcnt(0)" ::: "memory");
    __builtin_amdgcn_s_barrier();

    for (int i = 0; i < NT / 2; ++i) {
        int t  = 2 * i;
        int ts = (i < NT / 2 - 1) ? t + 2 : -1;
        TILE2PH(smem + (size_t)(t & 3) * 32768,       ts);
        TILE2PH(smem + (size_t)((t + 1) & 3) * 32768, (ts >= 0) ? ts + 1 : -1);
    }

    // epilogue: C/D layout col=lane&15, row=(lane>>4)*4+reg
    #pragma unroll
    for (int m = 0; m < 8; ++m) {
        int row0 = bm + wr * 128 + m * 16 + quad * 4;
        #pragma unroll
        for (int n = 0; n < 4; ++n) {
            int col = bn + wc * 64 + n * 16 + m16;
            #pragma unroll
            for (int r = 0; r < 4; ++r)
                C[(size_t)(row0 + r) * HD + col] = __float2bfloat16(acc[m][n][r]);
        }
    }
}

// ---------------------------------------------------------------------------
// bf16 MFMA GEMM (128x128 tile) — kept for the final 2048x768 projection.
template <bool BF16_OUT, bool SWIZ>
__global__ __launch_bounds__(256) void gemm_bf16_k(
    const bf16* __restrict__ A, const bf16* __restrict__ Bt,
    float* __restrict__ Cf, bf16* __restrict__ Cb, const float* __restrict__ bias)
{
    constexpr int K = HD;
    __shared__ __attribute__((aligned(16))) short As[128 * 32];
    __shared__ __attribute__((aligned(16))) short Bs[128 * 32];

    int bx, by;
    if (SWIZ) {
        int gid = blockIdx.x;
        int xcd = gid & 7, lid = gid >> 3;
        int sg = lid / 48, sl = lid - sg * 48;
        by = (xcd << 6) + (sg << 3) + (sl & 7);
        bx = sl >> 3;
    } else {
        bx = blockIdx.x; by = blockIdx.y;
    }

    int tid  = threadIdx.x;
    int wave = tid >> 6, lane = tid & 63;
    int wy = wave >> 1, wx = wave & 1;
    int m16 = lane & 15, quad = lane >> 4;
    int bm = by * 128;
    int bn = bx * 128;

    int p0 = wave * 128 + lane;
    int r0 = p0 >> 2, c0 = p0 & 3;
    int p1 = p0 + 64;
    int r1 = p1 >> 2, c1 = p1 & 3;

    const bf16* gA0 = A  + (size_t)(bm + r0) * K + c0 * 8;
    const bf16* gA1 = A  + (size_t)(bm + r1) * K + c1 * 8;
    const bf16* gB0 = Bt + (size_t)(bn + r0) * K + c0 * 8;
    const bf16* gB1 = Bt + (size_t)(bn + r1) * K + c1 * 8;

    f32x4 acc[4][4];
    #pragma unroll
    for (int i = 0; i < 4; i++)
        #pragma unroll
        for (int j = 0; j < 4; j++) acc[i][j] = (f32x4)0.f;

    const short8* Ac = (const short8*)As;
    const short8* Bc = (const short8*)Bs;

    for (int k0 = 0; k0 < K; k0 += 32) {
        load16_lds(gA0 + k0, &As[p0 * 8]);
        load16_lds(gA1 + k0, &As[p1 * 8]);
        load16_lds(gB0 + k0, &Bs[p0 * 8]);
        load16_lds(gB1 + k0, &Bs[p1 * 8]);
        __syncthreads();

        short8 a[4], b[4];
        #pragma unroll
        for (int i = 0; i < 4; i++)
            a[i] = Ac[(wy * 64 + i * 16 + m16) * 4 + quad];
        #pragma unroll
        for (int j = 0; j < 4; j++)
            b[j] = Bc[(wx * 64 + j * 16 + m16) * 4 + quad];
        #pragma unroll
        for (int i = 0; i < 4; i++)
            #pragma unroll
            for (int j = 0; j < 4; j++)
                acc[i][j] = __builtin_amdgcn_mfma_f32_16x16x32_bf16(a[i], b[j], acc[i][j], 0, 0, 0);
        __syncthreads();
    }

    #pragma unroll
    for (int j = 0; j < 4; j++) {
        int col = bn + wx * 64 + j * 16 + m16;
        float badd = (!BF16_OUT && bias) ? bias[col] : 0.f;
        #pragma unroll
        for (int i = 0; i < 4; i++) {
            int row0 = bm + wy * 64 + i * 16 + quad * 4;
            #pragma unroll
            for (int r = 0; r < 4; r++) {
                if (BF16_OUT)
                    Cb[(size_t)(row0 + r) * HD + col] = __float2bfloat16(acc[i][j][r]);
                else
                    Cf[(size_t)(row0 + r) * HD + col] = acc[i][j][r] + badd;
            }
        }
    }
}

// ---------------------------------------------------------------------------
// per-node attention logits: asrc[n][h] = dot(xw[n,h,:], att_src[h,:]).
// Wave per node (4 nodes/block): lane owns 12 contiguous channels (head=lane>>4,
// 16 lanes/head), 16-lane shuffle reduce. All 64 lanes active.
__device__ __forceinline__ float bflo(unsigned u) { return __uint_as_float(u << 16); }
__device__ __forceinline__ float bfhi(unsigned u) { return __uint_as_float(u & 0xffff0000u); }

__global__ __launch_bounds__(256) void alpha_k(
    const bf16* __restrict__ xw,
    const float* __restrict__ asl, const float* __restrict__ adl,
    float* __restrict__ asrc, float* __restrict__ adst)
{
    int wave = threadIdx.x >> 6, lane = threadIdx.x & 63;
    int n = blockIdx.x * 4 + wave;
    int c = lane * 12;                 // == head*192 + (lane&15)*12

    const bf16* row = xw + (size_t)n * HD + c;
    uint2 u0 = *(const uint2*)(row);
    uint2 u1 = *(const uint2*)(row + 4);
    uint2 u2 = *(const uint2*)(row + 8);
    float v[12] = {bflo(u0.x), bfhi(u0.x), bflo(u0.y), bfhi(u0.y),
                   bflo(u1.x), bfhi(u1.x), bflo(u1.y), bfhi(u1.y),
                   bflo(u2.x), bfhi(u2.x), bflo(u2.y), bfhi(u2.y)};

    float4 a0 = *(const float4*)(asl + c);
    float4 a1 = *(const float4*)(asl + c + 4);
    float4 a2 = *(const float4*)(asl + c + 8);
    float4 d0 = *(const float4*)(adl + c);
    float4 d1 = *(const float4*)(adl + c + 4);
    float4 d2 = *(const float4*)(adl + c + 8);
    float aa[12] = {a0.x,a0.y,a0.z,a0.w,a1.x,a1.y,a1.z,a1.w,a2.x,a2.y,a2.z,a2.w};
    float dd[12] = {d0.x,d0.y,d0.z,d0.w,d1.x,d1.y,d1.z,d1.w,d2.x,d2.y,d2.z,d2.w};

    float s1 = 0.f, s2 = 0.f;
    #pragma unroll
    for (int k = 0; k < 12; k++) { s1 += v[k] * aa[k]; s2 += v[k] * dd[k]; }

    #pragma unroll
    for (int off = 1; off < 16; off <<= 1) {
        s1 += __shfl_xor(s1, off, 64);
        s2 += __shfl_xor(s2, off, 64);
    }
    if ((lane & 15) == 0) {
        int head = lane >> 4;
        asrc[(size_t)n * HH + head] = s1;
        adst[(size_t)n * HH + head] = s2;
    }
}

// ---------------------------------------------------------------------------
// CSR build over dst
__global__ void hist_k(const int* __restrict__ ei, int* __restrict__ deg) {
    int e = blockIdx.x * 256 + threadIdx.x;   // grid == E2 exactly
    int dst = (e < EE) ? ei[EE + e] : (e - EE);
    atomicAdd(&deg[dst], 1);
}

__global__ void scan1_k(const int* __restrict__ deg, int* __restrict__ incl,
                        int* __restrict__ blocksum) {
    __shared__ int s[256];
    int t = threadIdx.x, n = blockIdx.x * 256 + t;
    int v = deg[n];
    s[t] = v;
    for (int off = 1; off < 256; off <<= 1) {
        __syncthreads();
        int tmp = (t >= off) ? s[t - off] : 0;
        __syncthreads();
        s[t] += tmp;
    }
    incl[n] = s[t];
    if (t == 255) blocksum[blockIdx.x] = s[255];
}

__global__ void scan2_k(const int* __restrict__ blocksum, int* __restrict__ blockoff) {
    __shared__ int s[256];
    int t = threadIdx.x;
    int v = blocksum[t];
    s[t] = v;
    for (int off = 1; off < 256; off <<= 1) {
        __syncthreads();
        int tmp = (t >= off) ? s[t - off] : 0;
        __syncthreads();
        s[t] += tmp;
    }
    blockoff[t] = s[t] - v;   // exclusive
}

__global__ void scan3_k(const int* __restrict__ deg, const int* __restrict__ blockoff,
                        int* __restrict__ incl_cursor, int* __restrict__ rowstart) {
    int t = threadIdx.x, n = blockIdx.x * 256 + t;
    int rs = blockoff[blockIdx.x] + incl_cursor[n] - deg[n];
    rowstart[n] = rs;
    incl_cursor[n] = rs;       // becomes the fill cursor
    if (n == 0) rowstart[NN] = E2;
}

__global__ void fill_k(const int* __restrict__ ei, int* __restrict__ cursor,
                       int* __restrict__ csr_src) {
    int e = blockIdx.x * 256 + threadIdx.x;
    int src = (e < EE) ? ei[e] : (e - EE);
    int dst = (e < EE) ? ei[EE + e] : (e - EE);
    int pos = atomicAdd(&cursor[dst], 1);
    csr_src[pos] = src;
}

// ---------------------------------------------------------------------------
// Fused GAT aggregation: edge softmax + weighted gather + bias + LayerNorm +
// ReLU + residual. One wave per node, zero barriers.
__global__ __launch_bounds__(256) void agg_k(
    const bf16* __restrict__ xw, const float4* __restrict__ asrc,
    const float4* __restrict__ adst, const int* __restrict__ rowstart,
    const int* __restrict__ csr_src,
    const float* __restrict__ bias_l, const float* __restrict__ gamma_l,
    const float* __restrict__ beta_l, const bf16* __restrict__ h_in,
    bf16* __restrict__ h_out)
{
    __shared__ float s_w[4][64][4];   // per-wave edge weights (4 heads)
    __shared__ int   s_src[4][64];    // per-wave edge sources

    int wave = threadIdx.x >> 6, lane = threadIdx.x & 63;
    int i = blockIdx.x * 4 + wave;    // node
    int c = lane * 12;                // channel base
    int myhead = lane >> 4;           // 16 lanes per head

    int r0 = rowstart[i], r1 = rowstart[i + 1];
    float4 ad = adst[i];

    float acc[12];
    #pragma unroll
    for (int k = 0; k < 12; k++) acc[k] = 0.f;
    float4 den = make_float4(0.f, 0.f, 0.f, 0.f);

    for (int base = r0; base < r1; base += 64) {
        int cnt = min(64, r1 - base);
        float4 w4 = make_float4(0.f, 0.f, 0.f, 0.f);
        if (lane < cnt) {
            int s = csr_src[base + lane];
            s_src[wave][lane] = s;
            float4 a = asrc[s];                       // L2-resident gather
            float t0 = a.x + ad.x; t0 = (t0 > 0.f) ? t0 : SLOPE * t0;
            float t1 = a.y + ad.y; t1 = (t1 > 0.f) ? t1 : SLOPE * t1;
            float t2 = a.z + ad.z; t2 = (t2 > 0.f) ? t2 : SLOPE * t2;
            float t3 = a.w + ad.w; t3 = (t3 > 0.f) ? t3 : SLOPE * t3;
            w4 = make_float4(__expf(t0), __expf(t1), __expf(t2), __expf(t3));
            *(float4*)&s_w[wave][lane][0] = w4;
        }
        den.x += w4.x; den.y += w4.y; den.z += w4.z; den.w += w4.w;
        for (int e = 0; e < cnt; e++) {
            int src = __builtin_amdgcn_readfirstlane(s_src[wave][e]);
            float wv = s_w[wave][e][myhead];          // broadcast read
            const bf16* row = xw + (size_t)src * HD + c;
            uint2 u0 = *(const uint2*)(row);
            uint2 u1 = *(const uint2*)(row + 4);
            uint2 u2 = *(const uint2*)(row + 8);
            acc[0] += wv * bflo(u0.x); acc[1]  += wv * bfhi(u0.x);
            acc[2] += wv * bflo(u0.y); acc[3]  += wv * bfhi(u0.y);
            acc[4] += wv * bflo(u1.x); acc[5]  += wv * bfhi(u1.x);
            acc[6] += wv * bflo(u1.y); acc[7]  += wv * bfhi(u1.y);
            acc[8] += wv * bflo(u2.x); acc[9]  += wv * bfhi(u2.x);
            acc[10] += wv * bflo(u2.y); acc[11] += wv * bfhi(u2.y);
        }
    }

    #pragma unroll
    for (int off = 32; off > 0; off >>= 1) {
        den.x += __shfl_xor(den.x, off, 64);
        den.y += __shfl_xor(den.y, off, 64);
        den.z += __shfl_xor(den.z, off, 64);
        den.w += __shfl_xor(den.w, off, 64);
    }
    float deni = (myhead == 0) ? den.x : (myhead == 1) ? den.y
               : (myhead == 2) ? den.z : den.w;
    float inv = 1.f / deni;

    float4 b0 = *(const float4*)(bias_l + c);
    float4 b1 = *(const float4*)(bias_l + c + 4);
    float4 b2 = *(const float4*)(bias_l + c + 8);
    float v[12];
    v[0] = acc[0] * inv + b0.x; v[1]  = acc[1] * inv + b0.y;
    v[2] = acc[2] * inv + b0.z; v[3]  = acc[3] * inv + b0.w;
    v[4] = acc[4] * inv + b1.x; v[5]  = acc[5] * inv + b1.y;
    v[6] = acc[6] * inv + b1.z; v[7]  = acc[7] * inv + b1.w;
    v[8] = acc[8] * inv + b2.x; v[9]  = acc[9] * inv + b2.y;
    v[10] = acc[10] * inv + b2.z; v[11] = acc[11] * inv + b2.w;

    float s = 0.f;
    #pragma unroll
    for (int k = 0; k < 12; k++) s += v[k];
    #pragma unroll
    for (int off = 32; off > 0; off >>= 1) s += __shfl_xor(s, off, 64);
    float mean = s * (1.f / (float)HD);

    float q = 0.f;
    #pragma unroll
    for (int k = 0; k < 12; k++) { float d = v[k] - mean; q += d * d; }
    #pragma unroll
    for (int off = 32; off > 0; off >>= 1) q += __shfl_xor(q, off, 64);
    float rs = rsqrtf(q * (1.f / (float)HD) + EPS);

    float4 g0 = *(const float4*)(gamma_l + c);
    float4 g1 = *(const float4*)(gamma_l + c + 4);
    float4 g2 = *(const float4*)(gamma_l + c + 8);
    float4 e0 = *(const float4*)(beta_l + c);
    float4 e1 = *(const float4*)(beta_l + c + 4);
    float4 e2 = *(const float4*)(beta_l + c + 8);
    float gg[12] = {g0.x,g0.y,g0.z,g0.w,g1.x,g1.y,g1.z,g1.w,g2.x,g2.y,g2.z,g2.w};
    float bb[12] = {e0.x,e0.y,e0.z,e0.w,e1.x,e1.y,e1.z,e1.w,e2.x,e2.y,e2.z,e2.w};

    const bf16* hrow = h_in + (size_t)i * HD + c;
    uint2 hu0 = *(const uint2*)(hrow);
    uint2 hu1 = *(const uint2*)(hrow + 4);
    uint2 hu2 = *(const uint2*)(hrow + 8);
    float hres[12] = {bflo(hu0.x), bfhi(hu0.x), bflo(hu0.y), bfhi(hu0.y),
                      bflo(hu1.x), bfhi(hu1.x), bflo(hu1.y), bfhi(hu1.y),
                      bflo(hu2.x), bfhi(hu2.x), bflo(hu2.y), bfhi(hu2.y)};

    bf16 pk[12];
    #pragma unroll
    for (int k = 0; k < 12; k++) {
        float o = fmaxf((v[k] - mean) * rs * gg[k] + bb[k], 0.f) + hres[k];
        pk[k] = __float2bfloat16(o);
    }
    bf16* orow = h_out + (size_t)i * HD + c;
    *(uint2*)(orow)     = *(const uint2*)&pk[0];
    *(uint2*)(orow + 4) = *(const uint2*)&pk[4];
    *(uint2*)(orow + 8) = *(const uint2*)&pk[8];
}

// ---------------------------------------------------------------------------
// global mean pool per graph -> bf16 hg; 192 threads, 4 ch/thread (uint2)
__global__ __launch_bounds__(192) void pool_k(
    const bf16* __restrict__ h, const int* __restrict__ bv,
    bf16* __restrict__ hg)
{
    int g = blockIdx.x, t = threadIdx.x;
    int lo = 0, hi = NN;
    while (lo < hi) { int mid = (lo + hi) >> 1; if (bv[mid] < g) lo = mid + 1; else hi = mid; }
    int start = lo;
    hi = NN;
    while (lo < hi) { int mid = (lo + hi) >> 1; if (bv[mid] < g + 1) lo = mid + 1; else hi = mid; }
    int end = lo;
    int c = t * 4;
    float a0 = 0.f, a1 = 0.f, a2 = 0.f, a3 = 0.f;
    for (int n = start; n < end; n++) {
        uint2 u = *(const uint2*)(h + (size_t)n * HD + c);
        a0 += bflo(u.x); a1 += bfhi(u.x); a2 += bflo(u.y); a3 += bfhi(u.y);
    }
    float sc = 1.f / fmaxf((float)(end - start), 1.f);
    bf16 pk[4];
    pk[0] = __float2bfloat16(a0 * sc); pk[1] = __float2bfloat16(a1 * sc);
    pk[2] = __float2bfloat16(a2 * sc); pk[3] = __float2bfloat16(a3 * sc);
    *(uint2*)(hg + (size_t)g * HD + c) = *(const uint2*)pk;
}

// ---------------------------------------------------------------------------
extern "C" void kernel_launch(void* const* d_in, const int* in_sizes, int n_in,
                              void* d_out, int out_size, void* d_ws, size_t ws_size,
                              hipStream_t stream)
{
    (void)in_sizes; (void)n_in; (void)out_size; (void)ws_size;
    const float* x       = (const float*)d_in[0];
    const int*   ei      = (const int*)d_in[1];
    const int*   bv      = (const int*)d_in[2];
    const float* W       = (const float*)d_in[3];
    const float* att_src = (const float*)d_in[4];
    const float* att_dst = (const float*)d_in[5];
    const float* bias    = (const float*)d_in[6];
    const float* gamma   = (const float*)d_in[7];
    const float* beta    = (const float*)d_in[8];
    const float* out_w   = (const float*)d_in[9];
    const float* out_b   = (const float*)d_in[10];
    float* out = (float*)d_out;

    char* p = (char*)d_ws;
    size_t off = 0;
    auto take = [&](size_t bytes) -> char* {
        char* r = p + off;
        off = (off + bytes + 255) & ~(size_t)255;
        return r;
    };
    bf16* xw        = (bf16*)take((size_t)NN * HD * 2);   // bf16 projected feats
    bf16* hbf0      = (bf16*)take((size_t)NN * HD * 2);   // h ping
    bf16* hbf1      = (bf16*)take((size_t)NN * HD * 2);   // h pong
    bf16* Wt3       = (bf16*)take((size_t)3 * HD * HD * 2); // W0,W1,out_w bf16^T
    float* asrc     = (float*)take((size_t)NN * HH * 4);
    float* adst     = (float*)take((size_t)NN * HH * 4);
    int*   deg      = (int*)take((size_t)NN * 4);
    int*   rowstart = (int*)take((size_t)(NN + 1) * 4);
    int*   cursor   = (int*)take((size_t)NN * 4);
    int*   blocksum = (int*)take(256 * 4);
    int*   blockoff = (int*)take(256 * 4);
    int*   csr_src  = (int*)take((size_t)E2 * 4);
    bf16*  hg       = (bf16*)take((size_t)BB * HD * 2);

    const int EB = E2 / 256;   // 1280, exact

    // ---- CSR build (topology only, once) ----
    zero_k<<<NN / 256, 256, 0, stream>>>((float*)deg, NN);
    hist_k<<<EB, 256, 0, stream>>>(ei, deg);
    scan1_k<<<NN / 256, 256, 0, stream>>>(deg, cursor, blocksum);
    scan2_k<<<1, 256, 0, stream>>>(blocksum, blockoff);
    scan3_k<<<NN / 256, 256, 0, stream>>>(deg, blockoff, cursor, rowstart);
    fill_k<<<EB, 256, 0, stream>>>(ei, cursor, csr_src);

    // ---- bf16 conversions ----
    conv_k<<<(NN * HD / 4 + 255) / 256, 256, 0, stream>>>((const float4*)x, hbf0, NN * HD / 4);
    wconv3_k<<<dim3(HD / 32, HD / 32, 3), 256, 0, stream>>>(W, out_w, Wt3);

    // ---- layers (ping-pong h buffers) ----
    bf16* hin = hbf0;
    bf16* hout = hbf1;
    for (int l = 0; l < LL; l++) {
        gemm256_k<<<768, 512, 0, stream>>>(hin, Wt3 + (size_t)l * HD * HD, xw);
        alpha_k<<<NN / 4, 256, 0, stream>>>(xw, att_src + (size_t)l * HH * DD,
                                            att_dst + (size_t)l * HH * DD, asrc, adst);
        agg_k<<<NN / 4, 256, 0, stream>>>(xw, (const float4*)asrc, (const float4*)adst,
                                          rowstart, csr_src,
                                          bias + (size_t)l * HD, gamma + (size_t)l * HD,
                                          beta + (size_t)l * HD, hin, hout);
        bf16* tmp = hin; hin = hout; hout = tmp;
    }

    // ---- pooling + output projection (bf16 MFMA, fp32 out) ----
    pool_k<<<BB, 192, 0, stream>>>(hin, bv, hg);
    gemm_bf16_k<false, false><<<dim3(HD / 128, BB / 128), 256, 0, stream>>>(
        hg, Wt3 + (size_t)2 * HD * HD, out, nullptr, out_b);
}